// Round 1
// baseline (865.834 us; speedup 1.0000x reference)
//
#include <hip/hip_runtime.h>
#include <cstdint>
#include <cstddef>

#define D_MODEL 1024
#define NH      16
#define HD      64
#define B_SZ    32
#define SEQ     1500
#define MROWS   (B_SZ * SEQ)   // 48000
#define KD      1024

typedef __attribute__((ext_vector_type(8))) short bf16x8;
typedef __attribute__((ext_vector_type(4))) float f32x4;
typedef unsigned short u16;

__device__ __forceinline__ u16 f2b(float f) {
  unsigned int x = __float_as_uint(f);
  x = (x + 0x7FFFu + ((x >> 16) & 1u)) >> 16;   // RNE
  return (u16)x;
}

// ---------------- cast f32 -> bf16 (8 elems/thread, 16B ld/st) ----------------
__global__ __launch_bounds__(256) void cast_f32_bf16(const float* __restrict__ src,
                                                     u16* __restrict__ dst, int n8) {
  int stride = gridDim.x * blockDim.x;
  for (int i = blockIdx.x * blockDim.x + threadIdx.x; i < n8; i += stride) {
    const float4* s = reinterpret_cast<const float4*>(src + (size_t)i * 8);
    float4 a = s[0], b = s[1];
    u16 u[8];
    u[0]=f2b(a.x); u[1]=f2b(a.y); u[2]=f2b(a.z); u[3]=f2b(a.w);
    u[4]=f2b(b.x); u[5]=f2b(b.y); u[6]=f2b(b.z); u[7]=f2b(b.w);
    *reinterpret_cast<uint4*>(dst + (size_t)i * 8) = *reinterpret_cast<const uint4*>(u);
  }
}

// ---------------- bf16 MFMA GEMM: C[m,n] = sum_k A[m,k]*Bmat[n,k] ----------------
// A: [48000][1024] bf16, Bmat: [2048][1024] bf16 (rows 0..1023 = Wk, 1024..2047 = Wv)
// n < 1024 -> Kout (no bias); n >= 1024 -> Vout (+bv)
#define BM 128
#define BN 128
#define BK 32

__global__ __launch_bounds__(256) void gemm_kv(const u16* __restrict__ A,
                                               const u16* __restrict__ Bmat,
                                               const float* __restrict__ bv,
                                               float* __restrict__ Kout,
                                               float* __restrict__ Vout) {
  __shared__ short As[BM][BK];
  __shared__ short Bs[BN][BK];

  // XCD-bijective swizzle: nwg = 6000, 6000 % 8 == 0
  const int nwg = gridDim.x;
  const int cpx = nwg >> 3;
  int bx = (blockIdx.x % 8) * cpx + (blockIdx.x / 8);

  const int mt = bx >> 4;          // 375 tiles
  const int nt = bx & 15;          // 16 tiles
  const int m0 = mt * BM;
  const int n0 = nt * BN;
  const int tid  = threadIdx.x;
  const int lane = tid & 63;
  const int wave = tid >> 6;
  const int wr = wave >> 1, wc = wave & 1;

  const int fr = lane & 15;        // fragment row/col
  const int kb = lane >> 4;        // k-block 0..3

  f32x4 acc[4][4] = {};

  for (int kt = 0; kt < KD / BK; ++kt) {
    const int k0 = kt * BK;
    #pragma unroll
    for (int it = 0; it < 2; ++it) {
      int idx = tid + it * 256;          // 0..511 16B-chunks
      int r = idx >> 2;
      int c = (idx & 3) * 8;
      const u16* ga = A + (size_t)(m0 + r) * KD + k0 + c;
      __builtin_amdgcn_global_load_lds((const __attribute__((address_space(1))) void*)ga,
          (__attribute__((address_space(3))) void*)(&As[0][0] + (size_t)idx * 8), 16, 0, 0);
      const u16* gb = Bmat + (size_t)(n0 + r) * KD + k0 + c;
      __builtin_amdgcn_global_load_lds((const __attribute__((address_space(1))) void*)gb,
          (__attribute__((address_space(3))) void*)(&Bs[0][0] + (size_t)idx * 8), 16, 0, 0);
    }
    __syncthreads();   // drains vmcnt before use

    bf16x8 af[4], bfr[4];
    #pragma unroll
    for (int m = 0; m < 4; ++m)
      af[m] = *reinterpret_cast<const bf16x8*>(&As[wr * 64 + m * 16 + fr][kb * 8]);
    #pragma unroll
    for (int n = 0; n < 4; ++n)
      bfr[n] = *reinterpret_cast<const bf16x8*>(&Bs[wc * 64 + n * 16 + fr][kb * 8]);

    #pragma unroll
    for (int m = 0; m < 4; ++m)
      #pragma unroll
      for (int n = 0; n < 4; ++n)
        acc[m][n] = __builtin_amdgcn_mfma_f32_16x16x32_bf16(af[m], bfr[n], acc[m][n], 0, 0, 0);
    __syncthreads();   // before overwriting LDS
  }

  // epilogue: C/D layout col = lane&15, row = (lane>>4)*4 + reg
  const bool isV = (n0 >= 1024);
  float* Co = isV ? Vout : Kout;
  const int ncol0 = isV ? (n0 - 1024) : n0;
  const int rbase = (lane >> 4) * 4;
  #pragma unroll
  for (int m = 0; m < 4; ++m) {
    #pragma unroll
    for (int n = 0; n < 4; ++n) {
      const int col = ncol0 + wc * 64 + n * 16 + fr;
      const float bias = isV ? bv[col] : 0.0f;
      #pragma unroll
      for (int r = 0; r < 4; ++r) {
        const int row = m0 + wr * 64 + m * 16 + rbase + r;
        Co[(size_t)row * D_MODEL + col] = acc[m][n][r] + bias;
      }
    }
  }
}

// ---------------- fp32 projection: out[b,n] = (dot(x[b], W[n]) + bias[n]) * scale ----------------
__global__ __launch_bounds__(256) void proj_kernel(const float* __restrict__ x,
                                                   const float* __restrict__ W,
                                                   const float* __restrict__ bias,
                                                   float scale, float* __restrict__ out) {
  const int b = blockIdx.x;
  const int tid = threadIdx.x;
  __shared__ float xs[D_MODEL];
  for (int i = tid; i < D_MODEL; i += 256) xs[i] = x[(size_t)b * D_MODEL + i];
  __syncthreads();
  for (int n = tid; n < D_MODEL; n += 256) {
    const float4* wp = reinterpret_cast<const float4*>(W + (size_t)n * D_MODEL);
    float acc = 0.f;
    #pragma unroll 4
    for (int i = 0; i < D_MODEL / 4; ++i) {
      float4 w = wp[i];
      acc += w.x * xs[4*i] + w.y * xs[4*i+1] + w.z * xs[4*i+2] + w.w * xs[4*i+3];
    }
    out[(size_t)b * D_MODEL + n] = (acc + bias[n]) * scale;
  }
}

// ---------------- attention: one block per (b,h) ----------------
__global__ __launch_bounds__(256) void attn_kernel(const float* __restrict__ qs,
                                                   const float* __restrict__ K,
                                                   const float* __restrict__ V,
                                                   float* __restrict__ attnc) {
  const int bh = blockIdx.x;
  const int b = bh >> 4;
  const int h = bh & 15;
  const int tid = threadIdx.x;
  __shared__ float sc[SEQ];
  __shared__ float q_sh[HD];
  __shared__ float red[256];
  __shared__ float pv[4][HD];

  if (tid < HD) q_sh[tid] = qs[(size_t)b * D_MODEL + h * HD + tid];
  __syncthreads();

  float lmax = -1e30f;
  for (int s = tid; s < SEQ; s += 256) {
    const float4* kp = reinterpret_cast<const float4*>(K + (size_t)(b * SEQ + s) * D_MODEL + h * HD);
    float acc = 0.f;
    #pragma unroll
    for (int i = 0; i < HD / 4; ++i) {
      float4 kv = kp[i];
      acc += kv.x * q_sh[4*i] + kv.y * q_sh[4*i+1] + kv.z * q_sh[4*i+2] + kv.w * q_sh[4*i+3];
    }
    sc[s] = acc;
    lmax = fmaxf(lmax, acc);
  }
  red[tid] = lmax; __syncthreads();
  for (int off = 128; off; off >>= 1) {
    if (tid < off) red[tid] = fmaxf(red[tid], red[tid + off]);
    __syncthreads();
  }
  const float mmax = red[0]; __syncthreads();

  float lsum = 0.f;
  for (int s = tid; s < SEQ; s += 256) {
    float p = __expf(sc[s] - mmax);
    sc[s] = p;
    lsum += p;
  }
  red[tid] = lsum; __syncthreads();
  for (int off = 128; off; off >>= 1) {
    if (tid < off) red[tid] += red[tid + off];
    __syncthreads();
  }
  const float inv = 1.0f / red[0];

  const int d = tid & 63;
  const int sg = tid >> 6;
  float acc = 0.f;
  for (int s = sg; s < SEQ; s += 4)
    acc += sc[s] * V[(size_t)(b * SEQ + s) * D_MODEL + h * HD + d];
  pv[sg][d] = acc;
  __syncthreads();
  if (tid < HD)
    attnc[(size_t)b * D_MODEL + h * HD + tid] =
        (pv[0][tid] + pv[1][tid] + pv[2][tid] + pv[3][tid]) * inv;
}

// ---------------- launch ----------------
extern "C" void kernel_launch(void* const* d_in, const int* in_sizes, int n_in,
                              void* d_out, int out_size, void* d_ws, size_t ws_size,
                              hipStream_t stream) {
  const float* hs  = (const float*)d_in[0];   // [32][1][1024]
  const float* enc = (const float*)d_in[1];   // [32][1500][1024]
  const float* Wq  = (const float*)d_in[2];
  const float* bq  = (const float*)d_in[3];
  const float* Wk  = (const float*)d_in[4];
  const float* Wv  = (const float*)d_in[5];
  const float* bv  = (const float*)d_in[6];
  const float* Wo  = (const float*)d_in[7];
  const float* bo  = (const float*)d_in[8];

  float* out   = (float*)d_out;
  float* attnO = out;                                  // [32*1024]
  float* Kout  = out + 32768;                          // [48000*1024]
  float* Vout  = Kout + (size_t)MROWS * D_MODEL;       // [48000*1024]

  // workspace layout (~102.8 MB)
  char* ws = (char*)d_ws;
  u16*   encb  = (u16*)ws;                             // 98,304,000 B
  u16*   wkvb  = (u16*)(ws + 98304000);                //  4,194,304 B
  float* qs    = (float*)(ws + 98304000 + 4194304);    //    131,072 B
  float* attnc = qs + 32768;                           //    131,072 B

  cast_f32_bf16<<<6144, 256, 0, stream>>>(enc, encb, MROWS * D_MODEL / 8);
  cast_f32_bf16<<<512, 256, 0, stream>>>(Wk, wkvb, D_MODEL * D_MODEL / 8);
  cast_f32_bf16<<<512, 256, 0, stream>>>(Wv, wkvb + (size_t)D_MODEL * D_MODEL, D_MODEL * D_MODEL / 8);

  gemm_kv<<<(MROWS / BM) * (2048 / BN), 256, 0, stream>>>(encb, wkvb, bv, Kout, Vout);

  // SCALE^2 = (64^-0.25)^2 = 1/8
  proj_kernel<<<B_SZ, 256, 0, stream>>>(hs, Wq, bq, 0.125f, qs);
  attn_kernel<<<B_SZ * NH, 256, 0, stream>>>(qs, Kout, Vout, attnc);
  proj_kernel<<<B_SZ, 256, 0, stream>>>(attnc, Wo, bo, 1.0f, attnO);
}

// Round 2
// 601.946 us; speedup vs baseline: 1.4384x; 1.4384x over previous
//
#include <hip/hip_runtime.h>
#include <cstdint>
#include <cstddef>

#define D_MODEL 1024
#define NH      16
#define HD      64
#define B_SZ    32
#define SEQ     1500
#define MROWS   (B_SZ * SEQ)   // 48000
#define KD      1024
#define MPAD    48128          // 188 * 256

typedef __attribute__((ext_vector_type(8))) short bf16x8;
typedef __attribute__((ext_vector_type(4))) float f32x4;
typedef unsigned short u16;

__device__ __forceinline__ u16 f2b(float f) {
  unsigned int x = __float_as_uint(f);
  x = (x + 0x7FFFu + ((x >> 16) & 1u)) >> 16;   // RNE
  return (u16)x;
}

// ---------------- cast f32 -> bf16 (8 elems/thread, 16B ld/st) ----------------
__global__ __launch_bounds__(256) void cast_f32_bf16(const float* __restrict__ src,
                                                     u16* __restrict__ dst, int n8) {
  int stride = gridDim.x * blockDim.x;
  for (int i = blockIdx.x * blockDim.x + threadIdx.x; i < n8; i += stride) {
    const float4* s = reinterpret_cast<const float4*>(src + (size_t)i * 8);
    float4 a = s[0], b = s[1];
    u16 u[8];
    u[0]=f2b(a.x); u[1]=f2b(a.y); u[2]=f2b(a.z); u[3]=f2b(a.w);
    u[4]=f2b(b.x); u[5]=f2b(b.y); u[6]=f2b(b.z); u[7]=f2b(b.w);
    *reinterpret_cast<uint4*>(dst + (size_t)i * 8) = *reinterpret_cast<const uint4*>(u);
  }
}

// ================= 256x256 8-phase bf16 MFMA GEMM =================
// C[m,n] = sum_k A[m,k] * Bmat[n,k];  A: [MPAD][1024] bf16, Bmat: [2048][1024] bf16
// n < 1024 -> Kout (no bias); n >= 1024 -> Vout (+bv).  Row-major LDS tiles
// [256][64] bf16 (128B rows), 16B-chunk XOR swizzle: chunk ^= (row & 7).
#define GBM 256
#define GBN 256
#define GBK 64
#define GNT (KD / GBK)   // 16 K-tiles

// Stage one A half-tile (region q: rows {q*64+[0,64), 128+q*64+[0,64)}) of K-tile kt.
__device__ __forceinline__ void stageA(const u16* __restrict__ Ag, u16* lbuf,
                                       long m0, int kt, int q, int tid) {
  #pragma unroll
  for (int L = 0; L < 2; ++L) {
    int c  = L * 512 + tid;            // chunk id 0..1023
    int rr = c >> 3, cp = c & 7;
    int trow = (rr & 63) + ((rr >> 6) << 7) + q * 64;
    int scp  = cp ^ (trow & 7);        // inverse-swizzled global chunk
    const u16* src = Ag + (m0 + trow) * (long)KD + kt * GBK + scp * 8;
    u16* dst = lbuf + (size_t)trow * GBK + cp * 8;
    __builtin_amdgcn_global_load_lds((const __attribute__((address_space(1))) void*)src,
        (__attribute__((address_space(3))) void*)dst, 16, 0, 0);
  }
}

// Stage one B half-tile (region r: rows {strip*64 + r*32 + [0,32)} for strip 0..3).
__device__ __forceinline__ void stageB(const u16* __restrict__ Bg, u16* lbuf,
                                       int n0, int kt, int r, int tid) {
  #pragma unroll
  for (int L = 0; L < 2; ++L) {
    int c  = L * 512 + tid;
    int rr = c >> 3, cp = c & 7;
    int trow = ((rr >> 5) << 6) + (rr & 31) + r * 32;
    int scp  = cp ^ (trow & 7);
    const u16* src = Bg + (size_t)(n0 + trow) * KD + kt * GBK + scp * 8;
    u16* dst = lbuf + (size_t)trow * GBK + cp * 8;
    __builtin_amdgcn_global_load_lds((const __attribute__((address_space(1))) void*)src,
        (__attribute__((address_space(3))) void*)dst, 16, 0, 0);
  }
}

__device__ __forceinline__ bf16x8 ldFrag(const u16* buf, int row, int kk, int lane) {
  int r  = row + (lane & 15);
  int ch = (kk * 4 + (lane >> 4)) ^ (r & 7);
  return *(const bf16x8*)(buf + (size_t)r * GBK + ch * 8);
}

__global__ __launch_bounds__(512, 2) void gemm_kv(const u16* __restrict__ A,
                                                  const u16* __restrict__ Bm,
                                                  const float* __restrict__ bv,
                                                  float* __restrict__ Kout,
                                                  float* __restrict__ Vout) {
  __shared__ u16 sA[2][GBM * GBK];   // 2 x 32 KB
  __shared__ u16 sB[2][GBN * GBK];   // 2 x 32 KB

  const int tid  = threadIdx.x;
  const int lane = tid & 63;
  const int wid  = tid >> 6;
  const int wr   = wid >> 2;         // 0..1  -> row half
  const int wc   = wid & 3;          // 0..3  -> col quarter

  // bijective XCD swizzle (1504 % 8 == 0), nt fastest within an XCD chunk
  int bx = (blockIdx.x & 7) * (gridDim.x >> 3) + (blockIdx.x >> 3);
  const int  mt = bx >> 3;           // 0..187
  const int  nt = bx & 7;            // 0..7
  const long m0 = (long)mt * GBM;
  const int  n0 = nt * GBN;

  // --- prologue: tile0 full -> buf0; tile1 AQ0,AQ1,BR0 -> buf1 (BR1(1) comes at t0.ph1)
  stageA(A, sA[0], m0, 0, 0, tid);
  stageA(A, sA[0], m0, 0, 1, tid);
  stageB(Bm, sB[0], n0, 0, 0, tid);
  stageB(Bm, sB[0], n0, 0, 1, tid);
  stageA(A, sA[1], m0, 1, 0, tid);
  stageA(A, sA[1], m0, 1, 1, tid);
  stageB(Bm, sB[1], n0, 1, 0, tid);
  asm volatile("s_waitcnt vmcnt(6)" ::: "memory");
  __builtin_amdgcn_s_barrier();

  bf16x8 af[8][2];     // all 8 M-frags x 2 k-halves kept
  bf16x8 bf2[2][2];    // current qn-pair of B-frags
  f32x4  acc[8][4] = {};

  for (int t = 0; t < GNT; ++t) {
    u16* cA = sA[t & 1];
    u16* cB = sB[t & 1];

    // ---- phase 1: read AQ0 (8) + BR0 (4); stage BR1(t+1) -> other B buf
    #pragma unroll
    for (int mf = 0; mf < 4; ++mf)
      #pragma unroll
      for (int kk = 0; kk < 2; ++kk)
        af[mf][kk] = ldFrag(cA, wr * 128 + mf * 16, kk, lane);
    #pragma unroll
    for (int nf = 0; nf < 2; ++nf)
      #pragma unroll
      for (int kk = 0; kk < 2; ++kk)
        bf2[nf][kk] = ldFrag(cB, wc * 64 + nf * 16, kk, lane);
    if (t + 1 < GNT) stageB(Bm, sB[(t + 1) & 1], n0, t + 1, 1, tid);
    __builtin_amdgcn_s_barrier();
    __builtin_amdgcn_s_setprio(1);
    #pragma unroll
    for (int mf = 0; mf < 4; ++mf)
      #pragma unroll
      for (int nf = 0; nf < 2; ++nf)
        #pragma unroll
        for (int kk = 0; kk < 2; ++kk)
          acc[mf][nf] = __builtin_amdgcn_mfma_f32_16x16x32_bf16(af[mf][kk], bf2[nf][kk], acc[mf][nf], 0, 0, 0);
    __builtin_amdgcn_s_setprio(0);
    __builtin_amdgcn_s_barrier();

    // ---- phase 2: read AQ1 (8); stage AQ0(t+2) -> this A buf (region free after ph1)
    #pragma unroll
    for (int mf = 4; mf < 8; ++mf)
      #pragma unroll
      for (int kk = 0; kk < 2; ++kk)
        af[mf][kk] = ldFrag(cA, wr * 128 + mf * 16, kk, lane);
    if (t + 2 < GNT) stageA(A, sA[t & 1], m0, t + 2, 0, tid);
    __builtin_amdgcn_s_barrier();
    __builtin_amdgcn_s_setprio(1);
    #pragma unroll
    for (int mf = 4; mf < 8; ++mf)
      #pragma unroll
      for (int nf = 0; nf < 2; ++nf)
        #pragma unroll
        for (int kk = 0; kk < 2; ++kk)
          acc[mf][nf] = __builtin_amdgcn_mfma_f32_16x16x32_bf16(af[mf][kk], bf2[nf][kk], acc[mf][nf], 0, 0, 0);
    __builtin_amdgcn_s_setprio(0);
    __builtin_amdgcn_s_barrier();

    // ---- phase 3: read BR1 (4); stage AQ1(t+2)
    #pragma unroll
    for (int nf = 0; nf < 2; ++nf)
      #pragma unroll
      for (int kk = 0; kk < 2; ++kk)
        bf2[nf][kk] = ldFrag(cB, wc * 64 + (nf + 2) * 16, kk, lane);
    if (t + 2 < GNT) stageA(A, sA[t & 1], m0, t + 2, 1, tid);
    __builtin_amdgcn_s_barrier();
    __builtin_amdgcn_s_setprio(1);
    #pragma unroll
    for (int mf = 0; mf < 4; ++mf)
      #pragma unroll
      for (int nf = 0; nf < 2; ++nf)
        #pragma unroll
        for (int kk = 0; kk < 2; ++kk)
          acc[mf][nf + 2] = __builtin_amdgcn_mfma_f32_16x16x32_bf16(af[mf][kk], bf2[nf][kk], acc[mf][nf + 2], 0, 0, 0);
    __builtin_amdgcn_s_setprio(0);
    __builtin_amdgcn_s_barrier();

    // ---- phase 4: stage BR0(t+2); counted vmcnt; MFMA qm1,qn1
    if (t + 2 < GNT) stageB(Bm, sB[t & 1], n0, t + 2, 0, tid);
    if (t < GNT - 2) { asm volatile("s_waitcnt vmcnt(6)" ::: "memory"); }
    else             { asm volatile("s_waitcnt vmcnt(0)" ::: "memory"); }
    __builtin_amdgcn_s_barrier();
    __builtin_amdgcn_s_setprio(1);
    #pragma unroll
    for (int mf = 4; mf < 8; ++mf)
      #pragma unroll
      for (int nf = 0; nf < 2; ++nf)
        #pragma unroll
        for (int kk = 0; kk < 2; ++kk)
          acc[mf][nf + 2] = __builtin_amdgcn_mfma_f32_16x16x32_bf16(af[mf][kk], bf2[nf][kk], acc[mf][nf + 2], 0, 0, 0);
    __builtin_amdgcn_s_setprio(0);
    __builtin_amdgcn_s_barrier();
  }

  // ---- epilogue: C/D layout col = lane&15, row = (lane>>4)*4 + reg
  const bool isV = (nt >= 4);
  float* Co = isV ? Vout : Kout;
  const int colbase = (isV ? n0 - 1024 : n0) + wc * 64 + (lane & 15);
  #pragma unroll
  for (int nf = 0; nf < 4; ++nf) {
    const int col = colbase + nf * 16;
    const float bias = isV ? bv[col] : 0.0f;
    #pragma unroll
    for (int mf = 0; mf < 8; ++mf) {
      const long rowb = m0 + wr * 128 + mf * 16 + (lane >> 4) * 4;
      #pragma unroll
      for (int r = 0; r < 4; ++r) {
        const long row = rowb + r;
        if (row < MROWS) Co[row * D_MODEL + col] = acc[mf][nf][r] + bias;
      }
    }
  }
}

// ---------------- attention with fused q-projection: one block per (b,h) ----------------
__global__ __launch_bounds__(256) void attn_kernel(const float* __restrict__ hs,
                                                   const float* __restrict__ Wq,
                                                   const float* __restrict__ bq,
                                                   const float* __restrict__ K,
                                                   const float* __restrict__ V,
                                                   float* __restrict__ attnc) {
  const int bh = blockIdx.x;
  const int b = bh >> 4;
  const int h = bh & 15;
  const int tid = threadIdx.x;
  __shared__ float xs[D_MODEL];
  __shared__ float qpart[4][HD];
  __shared__ float q_sh[HD];
  __shared__ float sc[SEQ];
  __shared__ float red[256];
  __shared__ float pv[4][HD];

  ((float4*)xs)[tid] = ((const float4*)(hs + (size_t)b * D_MODEL))[tid];
  __syncthreads();

  { // q-proj: 64 outputs, k split 4 ways; fold SCALE^2 = 1/8
    const int d = tid & 63, p = tid >> 6;
    const float4* wq4 = (const float4*)(Wq + (size_t)(h * HD + d) * D_MODEL + p * 256);
    const float4* xs4 = (const float4*)xs + p * 64;
    float a = 0.f;
    #pragma unroll 8
    for (int i = 0; i < 64; ++i) {
      float4 w = wq4[i], x = xs4[i];
      a += w.x * x.x + w.y * x.y + w.z * x.z + w.w * x.w;
    }
    qpart[p][d] = a;
  }
  __syncthreads();
  if (tid < HD)
    q_sh[tid] = (qpart[0][tid] + qpart[1][tid] + qpart[2][tid] + qpart[3][tid]
                 + bq[h * HD + tid]) * 0.125f;
  __syncthreads();

  float lmax = -1e30f;
  for (int s = tid; s < SEQ; s += 256) {
    const float4* kp = reinterpret_cast<const float4*>(K + (size_t)(b * SEQ + s) * D_MODEL + h * HD);
    float acc = 0.f;
    #pragma unroll
    for (int i = 0; i < HD / 4; ++i) {
      float4 kv = kp[i];
      acc += kv.x * q_sh[4*i] + kv.y * q_sh[4*i+1] + kv.z * q_sh[4*i+2] + kv.w * q_sh[4*i+3];
    }
    sc[s] = acc;
    lmax = fmaxf(lmax, acc);
  }
  red[tid] = lmax; __syncthreads();
  for (int off = 128; off; off >>= 1) {
    if (tid < off) red[tid] = fmaxf(red[tid], red[tid + off]);
    __syncthreads();
  }
  const float mmax = red[0]; __syncthreads();

  float lsum = 0.f;
  for (int s = tid; s < SEQ; s += 256) {
    float p = __expf(sc[s] - mmax);
    sc[s] = p;
    lsum += p;
  }
  red[tid] = lsum; __syncthreads();
  for (int off = 128; off; off >>= 1) {
    if (tid < off) red[tid] += red[tid + off];
    __syncthreads();
  }
  const float inv = 1.0f / red[0];

  const int d = tid & 63;
  const int sg = tid >> 6;
  float acc = 0.f;
  for (int s = sg; s < SEQ; s += 4)
    acc += sc[s] * V[(size_t)(b * SEQ + s) * D_MODEL + h * HD + d];
  pv[sg][d] = acc;
  __syncthreads();
  if (tid < HD)
    attnc[(size_t)b * D_MODEL + h * HD + tid] =
        (pv[0][tid] + pv[1][tid] + pv[2][tid] + pv[3][tid]) * inv;
}

// ---------------- o-projection: 8 blocks per batch, k split 2 ----------------
__global__ __launch_bounds__(256) void oproj_kernel(const float* __restrict__ x,
                                                    const float* __restrict__ Wo,
                                                    const float* __restrict__ bo,
                                                    float* __restrict__ out) {
  const int b = blockIdx.x >> 3, ch = blockIdx.x & 7;
  const int tid = threadIdx.x;
  __shared__ float xs[D_MODEL];
  ((float4*)xs)[tid] = ((const float4*)(x + (size_t)b * D_MODEL))[tid];
  __syncthreads();
  const int n = ch * 128 + (tid >> 1);
  const int half = tid & 1;
  const float4* wp = (const float4*)(Wo + (size_t)n * D_MODEL + half * 512);
  const float4* xp = (const float4*)xs + half * 128;
  float a = 0.f;
  #pragma unroll 8
  for (int i = 0; i < 128; ++i) {
    float4 w = wp[i], xv = xp[i];
    a += w.x * xv.x + w.y * xv.y + w.z * xv.z + w.w * xv.w;
  }
  a += __shfl_xor(a, 1);
  if (!half) out[(size_t)b * D_MODEL + n] = a + bo[n];
}

// ---------------- launch ----------------
extern "C" void kernel_launch(void* const* d_in, const int* in_sizes, int n_in,
                              void* d_out, int out_size, void* d_ws, size_t ws_size,
                              hipStream_t stream) {
  const float* hs  = (const float*)d_in[0];
  const float* enc = (const float*)d_in[1];
  const float* Wq  = (const float*)d_in[2];
  const float* bq  = (const float*)d_in[3];
  const float* Wk  = (const float*)d_in[4];
  const float* Wv  = (const float*)d_in[5];
  const float* bv  = (const float*)d_in[6];
  const float* Wo  = (const float*)d_in[7];
  const float* bo  = (const float*)d_in[8];

  float* out   = (float*)d_out;
  float* attnO = out;
  float* Kout  = out + 32768;
  float* Vout  = Kout + (size_t)MROWS * D_MODEL;

  char* ws = (char*)d_ws;
  u16*   encb  = (u16*)ws;                                   // MPAD*1024*2 = 98,566,144 B
  u16*   wkvb  = (u16*)(ws + (size_t)MPAD * D_MODEL * 2);    // 4,194,304 B
  float* attnc = (float*)(ws + (size_t)MPAD * D_MODEL * 2 + 4194304);  // 131,072 B

  cast_f32_bf16<<<6144, 256, 0, stream>>>(enc, encb, MROWS * D_MODEL / 8);
  cast_f32_bf16<<<512, 256, 0, stream>>>(Wk, wkvb, D_MODEL * D_MODEL / 8);
  cast_f32_bf16<<<512, 256, 0, stream>>>(Wv, wkvb + (size_t)D_MODEL * D_MODEL, D_MODEL * D_MODEL / 8);

  gemm_kv<<<(MPAD / GBM) * (2048 / GBN), 512, 0, stream>>>(encb, wkvb, bv, Kout, Vout);

  attn_kernel<<<B_SZ * NH, 256, 0, stream>>>(hs, Wq, bq, Kout, Vout, attnc);
  oproj_kernel<<<B_SZ * 8, 256, 0, stream>>>(attnc, Wo, bo, attnO);
}

// Round 3
// 540.263 us; speedup vs baseline: 1.6026x; 1.1142x over previous
//
#include <hip/hip_runtime.h>
#include <cstdint>
#include <cstddef>

#define D_MODEL 1024
#define NH      16
#define HD      64
#define B_SZ    32
#define SEQ     1500
#define MROWS   (B_SZ * SEQ)   // 48000
#define KD      1024

typedef __attribute__((ext_vector_type(8))) short bf16x8;
typedef __attribute__((ext_vector_type(4))) float f32x4;
typedef unsigned short u16;

__device__ __forceinline__ u16 f2b(float f) {
  unsigned int x = __float_as_uint(f);
  x = (x + 0x7FFFu + ((x >> 16) & 1u)) >> 16;   // RNE
  return (u16)x;
}

// ---------------- fused cast f32 -> bf16 (enc, Wk, Wv in one launch) ----------------
__global__ __launch_bounds__(256) void cast_all(const float* __restrict__ enc,
                                                const float* __restrict__ Wk,
                                                const float* __restrict__ Wv,
                                                u16* __restrict__ encb,
                                                u16* __restrict__ wkvb) {
  const int NA = MROWS * KD / 8;   // 6,144,000
  const int NW = KD * KD / 8;      // 131,072
  int stride = gridDim.x * blockDim.x;
  for (int i = blockIdx.x * blockDim.x + threadIdx.x; i < NA + 2 * NW; i += stride) {
    const float* s; u16* d;
    if (i < NA)            { s = enc + (size_t)i * 8;            d = encb + (size_t)i * 8; }
    else if (i < NA + NW)  { size_t j = i - NA;      s = Wk + j * 8; d = wkvb + j * 8; }
    else                   { size_t j = i - NA - NW; s = Wv + j * 8; d = wkvb + (size_t)NW * 8 + j * 8; }
    const float4* s4 = reinterpret_cast<const float4*>(s);
    float4 a = s4[0], b = s4[1];
    u16 u[8];
    u[0]=f2b(a.x); u[1]=f2b(a.y); u[2]=f2b(a.z); u[3]=f2b(a.w);
    u[4]=f2b(b.x); u[5]=f2b(b.y); u[6]=f2b(b.z); u[7]=f2b(b.w);
    *reinterpret_cast<uint4*>(d) = *reinterpret_cast<const uint4*>(u);
  }
}

// ================= 128x256 bf16 MFMA GEMM, 2 blocks/CU =================
// C[m,n] = sum_k A[m,k]*Bmat[n,k]; A [48000][1024] bf16, Bmat [2048][1024] bf16.
// nt<4 -> Kout (no bias), nt>=4 -> Vout (+bv). BK=32; LDS rows 64 B,
// 16B-chunk swizzle cp ^= (r>>1)&3 (2-way bank aliasing = free).
#define GBM 128
#define GBN 256
#define GBK 32
#define GNT (KD / GBK)   // 32 K-tiles

__device__ __forceinline__ void stageA(const u16* __restrict__ Ag, u16* lbuf,
                                       long m0, int kt, int tid) {
  int c = tid;                        // 512 chunks of 16B (128 rows x 4)
  int r = c >> 2, cp = c & 3;
  int scp = cp ^ ((r >> 1) & 3);
  const u16* src = Ag + (m0 + r) * (long)KD + kt * GBK + scp * 8;
  __builtin_amdgcn_global_load_lds((const __attribute__((address_space(1))) void*)src,
      (__attribute__((address_space(3))) void*)(lbuf + (size_t)c * 8), 16, 0, 0);
}

__device__ __forceinline__ void stageB(const u16* __restrict__ Bg, u16* lbuf,
                                       int n0, int kt, int tid) {
  #pragma unroll
  for (int L = 0; L < 2; ++L) {
    int c = tid + L * 512;            // 1024 chunks (256 rows x 4)
    int r = c >> 2, cp = c & 3;
    int scp = cp ^ ((r >> 1) & 3);
    const u16* src = Bg + (size_t)(n0 + r) * KD + kt * GBK + scp * 8;
    __builtin_amdgcn_global_load_lds((const __attribute__((address_space(1))) void*)src,
        (__attribute__((address_space(3))) void*)(lbuf + (size_t)c * 8), 16, 0, 0);
  }
}

__device__ __forceinline__ bf16x8 ldFrag(const u16* buf, int row, int lane) {
  int r  = row + (lane & 15);
  int ch = (lane >> 4) ^ ((r >> 1) & 3);
  return *(const bf16x8*)(buf + (size_t)r * GBK + ch * 8);
}

__global__ __launch_bounds__(512, 4) void gemm_kv(const u16* __restrict__ A,
                                                  const u16* __restrict__ Bm,
                                                  const float* __restrict__ bv,
                                                  float* __restrict__ Kout,
                                                  float* __restrict__ Vout) {
  __shared__ __align__(16) char smem[2 * (GBM + GBN) * GBK * 2];   // 48 KiB
  u16* sA0 = (u16*)smem;                // 8 KB
  u16* sA1 = sA0 + GBM * GBK;           // 8 KB
  u16* sB0 = sA1 + GBM * GBK;           // 16 KB
  u16* sB1 = sB0 + GBN * GBK;           // 16 KB

  const int tid  = threadIdx.x;
  const int lane = tid & 63;
  const int wid  = tid >> 6;
  const int wr   = wid >> 2;            // 0..1: 64-row half
  const int wc   = wid & 3;             // 0..3: 64-col quarter

  // bijective XCD swizzle (grid 3000 % 8 == 0); nt fastest within a chunk
  int bx = (blockIdx.x & 7) * (gridDim.x >> 3) + (blockIdx.x >> 3);
  const int  mt = bx >> 3;              // 0..374
  const int  nt = bx & 7;               // 0..7
  const long m0 = (long)mt * GBM;
  const int  n0 = nt * GBN;

  // prologue: tiles 0,1 (3 loads/thread each)
  stageA(A, sA0, m0, 0, tid);
  stageB(Bm, sB0, n0, 0, tid);
  stageA(A, sA1, m0, 1, tid);
  stageB(Bm, sB1, n0, 1, tid);

  f32x4 acc[4][4] = {};

  for (int t = 0; t < GNT; ++t) {
    if (t == GNT - 1) { asm volatile("s_waitcnt vmcnt(0)" ::: "memory"); }
    else              { asm volatile("s_waitcnt vmcnt(3)" ::: "memory"); }
    __builtin_amdgcn_s_barrier();

    const u16* cA = (t & 1) ? sA1 : sA0;
    const u16* cB = (t & 1) ? sB1 : sB0;
    bf16x8 af[4], bfr[4];
    #pragma unroll
    for (int mf = 0; mf < 4; ++mf) af[mf]  = ldFrag(cA, wr * 64 + mf * 16, lane);
    #pragma unroll
    for (int nf = 0; nf < 4; ++nf) bfr[nf] = ldFrag(cB, wc * 64 + nf * 16, lane);
    asm volatile("s_waitcnt lgkmcnt(0)" ::: "memory");
    __builtin_amdgcn_s_barrier();

    // prefetch tile t+2 into the buffer just consumed
    if (t + 2 < GNT) {
      u16* pA = (t & 1) ? sA1 : sA0;
      u16* pB = (t & 1) ? sB1 : sB0;
      stageA(A, pA, m0, t + 2, tid);
      stageB(Bm, pB, n0, t + 2, tid);
    }

    #pragma unroll
    for (int mf = 0; mf < 4; ++mf)
      #pragma unroll
      for (int nf = 0; nf < 4; ++nf)
        acc[mf][nf] = __builtin_amdgcn_mfma_f32_16x16x32_bf16(af[mf], bfr[nf], acc[mf][nf], 0, 0, 0);
  }

  // ---- coalesced epilogue via LDS transpose (reuse smem as [32][260] f32) ----
  __syncthreads();
  float (*ep)[260] = (float(*)[260])smem;   // 33,280 B

  const bool isV = (nt >= 4);
  float* Co = isV ? Vout : Kout;
  const int ncol0 = isV ? (n0 - 1024) : n0;
  float4 bias4[4];
  #pragma unroll
  for (int k = 0; k < 4; ++k) {
    int c4 = (tid + 512 * k) & 63;
    bias4[k] = isV ? reinterpret_cast<const float4*>(bv)[(ncol0 >> 2) + c4]
                   : make_float4(0.f, 0.f, 0.f, 0.f);
  }

  #pragma unroll
  for (int p = 0; p < 4; ++p) {         // 32-row slabs of the 128-row block
    if (wr == (p >> 1)) {
      const int mfb = (p & 1) * 2;
      #pragma unroll
      for (int mm = 0; mm < 2; ++mm)
        #pragma unroll
        for (int nf = 0; nf < 4; ++nf)
          #pragma unroll
          for (int r = 0; r < 4; ++r)
            ep[mm * 16 + (lane >> 4) * 4 + r][wc * 64 + nf * 16 + (lane & 15)] =
                acc[mfb + mm][nf][r];
    }
    __syncthreads();
    #pragma unroll
    for (int k = 0; k < 4; ++k) {
      int idx = tid + 512 * k;          // 0..2047 float4s
      int row = idx >> 6;               // 0..31
      int c4  = idx & 63;
      long grow = m0 + p * 32 + row;
      float4 v = *reinterpret_cast<const float4*>(&ep[row][c4 * 4]);
      v.x += bias4[k].x; v.y += bias4[k].y; v.z += bias4[k].z; v.w += bias4[k].w;
      *reinterpret_cast<float4*>(&Co[grow * D_MODEL + ncol0 + c4 * 4]) = v;
    }
    __syncthreads();
  }
}

// ---------------- attention with fused q-projection: one block per (b,h) ----------------
__global__ __launch_bounds__(256) void attn_kernel(const float* __restrict__ hs,
                                                   const float* __restrict__ Wq,
                                                   const float* __restrict__ bq,
                                                   const float* __restrict__ K,
                                                   const float* __restrict__ V,
                                                   float* __restrict__ attnc) {
  const int bh = blockIdx.x;
  const int b = bh >> 4;
  const int h = bh & 15;
  const int tid = threadIdx.x;
  __shared__ float xs[D_MODEL];
  __shared__ float qpart[4][HD];
  __shared__ float q_sh[HD];
  __shared__ float sc[SEQ];
  __shared__ float red[256];
  __shared__ float pv[4][HD];

  ((float4*)xs)[tid] = ((const float4*)(hs + (size_t)b * D_MODEL))[tid];
  __syncthreads();

  { // q-proj: 64 outputs, k split 4 ways; fold SCALE^2 = 1/8
    const int d = tid & 63, p = tid >> 6;
    const float4* wq4 = (const float4*)(Wq + (size_t)(h * HD + d) * D_MODEL + p * 256);
    const float4* xs4 = (const float4*)xs + p * 64;
    float a = 0.f;
    #pragma unroll 8
    for (int i = 0; i < 64; ++i) {
      float4 w = wq4[i], x = xs4[i];
      a += w.x * x.x + w.y * x.y + w.z * x.z + w.w * x.w;
    }
    qpart[p][d] = a;
  }
  __syncthreads();
  if (tid < HD)
    q_sh[tid] = (qpart[0][tid] + qpart[1][tid] + qpart[2][tid] + qpart[3][tid]
                 + bq[h * HD + tid]) * 0.125f;
  __syncthreads();

  float lmax = -1e30f;
  for (int s = tid; s < SEQ; s += 256) {
    const float4* kp = reinterpret_cast<const float4*>(K + (size_t)(b * SEQ + s) * D_MODEL + h * HD);
    float acc = 0.f;
    #pragma unroll
    for (int i = 0; i < HD / 4; ++i) {
      float4 kv = kp[i];
      acc += kv.x * q_sh[4*i] + kv.y * q_sh[4*i+1] + kv.z * q_sh[4*i+2] + kv.w * q_sh[4*i+3];
    }
    sc[s] = acc;
    lmax = fmaxf(lmax, acc);
  }
  red[tid] = lmax; __syncthreads();
  for (int off = 128; off; off >>= 1) {
    if (tid < off) red[tid] = fmaxf(red[tid], red[tid + off]);
    __syncthreads();
  }
  const float mmax = red[0]; __syncthreads();

  float lsum = 0.f;
  for (int s = tid; s < SEQ; s += 256) {
    float p = __expf(sc[s] - mmax);
    sc[s] = p;
    lsum += p;
  }
  red[tid] = lsum; __syncthreads();
  for (int off = 128; off; off >>= 1) {
    if (tid < off) red[tid] += red[tid + off];
    __syncthreads();
  }
  const float inv = 1.0f / red[0];

  const int d = tid & 63;
  const int sg = tid >> 6;
  float acc = 0.f;
  for (int s = sg; s < SEQ; s += 4)
    acc += sc[s] * V[(size_t)(b * SEQ + s) * D_MODEL + h * HD + d];
  pv[sg][d] = acc;
  __syncthreads();
  if (tid < HD)
    attnc[(size_t)b * D_MODEL + h * HD + tid] =
        (pv[0][tid] + pv[1][tid] + pv[2][tid] + pv[3][tid]) * inv;
}

// ---------------- o-projection: 8 blocks per batch, k split 2 ----------------
__global__ __launch_bounds__(256) void oproj_kernel(const float* __restrict__ x,
                                                    const float* __restrict__ Wo,
                                                    const float* __restrict__ bo,
                                                    float* __restrict__ out) {
  const int b = blockIdx.x >> 3, ch = blockIdx.x & 7;
  const int tid = threadIdx.x;
  __shared__ float xs[D_MODEL];
  ((float4*)xs)[tid] = ((const float4*)(x + (size_t)b * D_MODEL))[tid];
  __syncthreads();
  const int n = ch * 128 + (tid >> 1);
  const int half = tid & 1;
  const float4* wp = (const float4*)(Wo + (size_t)n * D_MODEL + half * 512);
  const float4* xp = (const float4*)xs + half * 128;
  float a = 0.f;
  #pragma unroll 8
  for (int i = 0; i < 128; ++i) {
    float4 w = wp[i], xv = xp[i];
    a += w.x * xv.x + w.y * xv.y + w.z * xv.z + w.w * xv.w;
  }
  a += __shfl_xor(a, 1);
  if (!half) out[(size_t)b * D_MODEL + n] = a + bo[n];
}

// ---------------- launch ----------------
extern "C" void kernel_launch(void* const* d_in, const int* in_sizes, int n_in,
                              void* d_out, int out_size, void* d_ws, size_t ws_size,
                              hipStream_t stream) {
  const float* hs  = (const float*)d_in[0];
  const float* enc = (const float*)d_in[1];
  const float* Wq  = (const float*)d_in[2];
  const float* bq  = (const float*)d_in[3];
  const float* Wk  = (const float*)d_in[4];
  const float* Wv  = (const float*)d_in[5];
  const float* bv  = (const float*)d_in[6];
  const float* Wo  = (const float*)d_in[7];
  const float* bo  = (const float*)d_in[8];

  float* out   = (float*)d_out;
  float* attnO = out;
  float* Kout  = out + 32768;
  float* Vout  = Kout + (size_t)MROWS * D_MODEL;

  char* ws = (char*)d_ws;
  u16*   encb  = (u16*)ws;                                    // 98,304,000 B
  u16*   wkvb  = (u16*)(ws + (size_t)MROWS * D_MODEL * 2);    //  4,194,304 B
  float* attnc = (float*)(ws + (size_t)MROWS * D_MODEL * 2 + 4194304);  // 131,072 B

  cast_all<<<3072, 256, 0, stream>>>(enc, Wk, Wv, encb, wkvb);

  gemm_kv<<<(MROWS / GBM) * (2048 / GBN), 512, 0, stream>>>(encb, wkvb, bv, Kout, Vout);

  attn_kernel<<<B_SZ * NH, 256, 0, stream>>>(hs, Wq, bq, Kout, Vout, attnc);
  oproj_kernel<<<B_SZ * 8, 256, 0, stream>>>(attnc, Wo, bo, attnO);
}